// Round 13
// baseline (137.301 us; speedup 1.0000x reference)
//
#include <hip/hip_runtime.h>

#define TT 4
#define BB 32
#define DD 512
#define NN 576
#define EE 16
#define DC 8
#define DCH 64              // D-values per chunk
#define CC 144
#define ROW (EE*CC)         // 2304
#define SZ 42467328UL       // B*N*E*C
#define ZF4PB 82944         // f4 zeros per zero-block: 2*SZ/4/256

typedef float f4 __attribute__((ext_vector_type(4)));

// ---------------- Kernel 1: partial logits + block-specialized zero-fill ----------------
// grid 512, block 576. Blocks 0..255: R10's k_part body exactly (b=blk&31,
// dc=blk>>5). Blocks 256..511: zero-fill 1/256th of out[0..2*SZ) with plain f4
// stores (fill-kernel pattern). Read-waves and write-waves live on the same CU
// but in different blocks -> no shared vmcnt, reads and writes flow concurrently.
__global__ __launch_bounds__(576) void k_partzero(const float* __restrict__ x,
                                                  const float* __restrict__ w,
                                                  float* __restrict__ part,
                                                  float* __restrict__ out) {
  const int blk = blockIdx.x;
  const int n   = threadIdx.x;

  if (blk >= 256) {
    // ---- zero role ----
    const int zid = blk - 256;
    f4* outz = (f4*)out + (size_t)zid * ZF4PB + n;
    const f4 zv = {0.f, 0.f, 0.f, 0.f};
#pragma unroll 8
    for (int k = 0; k < 144; ++k)
      outz[(size_t)k * 576] = zv;
    return;
  }

  // ---- part role (R10 body, unchanged) ----
  const int b  = blk & 31;
  const int dc = blk >> 5;
  const int d0 = dc * DCH;

  const float* xp = x + ((size_t)b * DD + d0) * NN + n;
  const size_t TS = (size_t)BB * DD * NN;   // t-plane stride in floats

  float acc[EE];
#pragma unroll
  for (int e = 0; e < EE; ++e) acc[e] = 0.f;

#pragma unroll 2
  for (int dd = 0; dd < DCH; ++dd) {
    const size_t o = (size_t)dd * NN;
    const float x0 = xp[o];
    const float x1 = xp[o + TS];
    const float x2 = xp[o + 2 * TS];
    const float x3 = xp[o + 3 * TS];
    const float xs = (x0 + x1) + (x2 + x3);
    const float* wd = w + (size_t)(d0 + dd) * EE;   // wave-uniform -> s_load
#pragma unroll
    for (int e = 0; e < EE; ++e) acc[e] = fmaf(xs, wd[e], acc[e]);
  }

  float4* dst4 = (float4*)(part + (((size_t)b * NN + n) * DC + dc) * EE);
#pragma unroll
  for (int q = 0; q < 4; ++q)
    dst4[q] = make_float4(acc[4*q], acc[4*q+1], acc[4*q+2], acc[4*q+3]);
}

// ---------------- Kernel 2: softmax, top-2, capacity scan (ballot-based) ----------------
// grid 32 (one per b), block 576 (one per token).
__global__ __launch_bounds__(576) void k_gate(const float* __restrict__ part,
                                              float4* __restrict__ info,
                                              float* __restrict__ lossp) {
  const int b = blockIdx.x;
  const int n = threadIdx.x;
  const int wave = n >> 6, lane = n & 63;

  __shared__ float sprox[9][EE];
  __shared__ int   swc1[9][EE];
  __shared__ int   swc2[9][EE];
  __shared__ int   woff1[9][EE];
  __shared__ int   woff2[9][EE];
  __shared__ float sproxTot[EE];
  __shared__ int   scnt0[EE];
  __shared__ int   sbase2[EE];

  // reduce partials -> logits (mean over T folded as *0.25)
  float l[EE];
#pragma unroll
  for (int e = 0; e < EE; ++e) l[e] = 0.f;
  {
    const float4* p4 = (const float4*)(part + (size_t)(b * NN + n) * (DC * EE));
#pragma unroll
    for (int dc = 0; dc < DC; ++dc) {
#pragma unroll
      for (int q = 0; q < 4; ++q) {
        float4 v = p4[dc * 4 + q];
        l[4*q+0] += v.x; l[4*q+1] += v.y; l[4*q+2] += v.z; l[4*q+3] += v.w;
      }
    }
#pragma unroll
    for (int e = 0; e < EE; ++e) l[e] *= 0.25f;
  }

  // softmax
  float m = l[0];
#pragma unroll
  for (int e = 1; e < EE; ++e) m = fmaxf(m, l[e]);
  float raw[EE]; float s = 0.f;
#pragma unroll
  for (int e = 0; e < EE; ++e) { raw[e] = expf(l[e] - m); s += raw[e]; }
  float inv = 1.f / s;
#pragma unroll
  for (int e = 0; e < EE; ++e) raw[e] *= inv;

  // top-1 / top-2 (first-index tie-break, matching jnp.argmax)
  int e1 = 0; float g1 = raw[0];
#pragma unroll
  for (int e = 1; e < EE; ++e) if (raw[e] > g1) { g1 = raw[e]; e1 = e; }
  int e2 = (e1 == 0) ? 1 : 0; float g2 = raw[e2];
#pragma unroll
  for (int e = 0; e < EE; ++e) if (e != e1 && raw[e] > g2) { g2 = raw[e]; e2 = e; }
  const float denom = g1 + g2 + 1e-9f;
  const float w0 = g1 / denom, w1 = g2 / denom;

  // ballot-based per-expert ranks: for each expert, 64-bit membership mask
  const unsigned long long ltm = (1ull << lane) - 1ull;
  int pre1 = 0, pre2 = 0;
#pragma unroll
  for (int e = 0; e < EE; ++e) {
    unsigned long long m1 = __ballot(e1 == e);
    unsigned long long m2 = __ballot(e2 == e);
    if (lane == 0) { swc1[wave][e] = __popcll(m1); swc2[wave][e] = __popcll(m2); }
    if (e == e1) pre1 = __popcll(m1 & ltm);
    if (e == e2) pre2 = __popcll(m2 & ltm);
  }

  // per-wave proxy (softmax sums) reduce
#pragma unroll
  for (int e = 0; e < EE; ++e) {
    float v = raw[e];
#pragma unroll
    for (int off = 32; off; off >>= 1) v += __shfl_xor(v, off);
    if (lane == 0) sprox[wave][e] = v;
  }
  __syncthreads();

  // cross-wave exclusive scan per expert (16 threads, 9 iters each)
  if (n < EE) {
    int r1 = 0, r2 = 0; float pv = 0.f;
#pragma unroll
    for (int wv = 0; wv < 9; ++wv) {
      woff1[wv][n] = r1; r1 += swc1[wv][n];
      woff2[wv][n] = r2; r2 += swc2[wv][n];
      pv += sprox[wv][n];
    }
    scnt0[n]    = r1;                     // pre-capacity top-1 count (for loss)
    sbase2[n]   = r1 < CC ? r1 : CC;      // post-truncation kept count (k=1 base)
    sproxTot[n] = pv;
  }
  __syncthreads();

  if (n == 0) {
    float S = 0.f;
    for (int e = 0; e < EE; ++e) S += sproxTot[e] * (float)scnt0[e];
    lossp[b] = S / ((float)NN * (float)NN);
  }

  const int p0 = woff1[wave][e1] + pre1;
  const int p1 = sbase2[e2] + woff2[wave][e2] + pre2;

  const int  pos0 = (p0 < CC) ? (e1 * CC + p0) : -1;
  const int  pos1 = (p1 < CC) ? (e2 * CC + p1) : -1;
  const float w0k = (p0 < CC) ? w0 : 0.f;
  const float w1k = (p1 < CC) ? w1 : 0.f;

  float4 o;
  o.x = __int_as_float(pos0);
  o.y = w0k;
  o.z = __int_as_float(pos1);
  o.w = w1k;
  info[b * NN + n] = o;
}

// ---------------- Kernel 3: sparse scatter of nonzeros + loss ----------------
// grid 36 x 512: one thread per token; <=4 scattered dword stores each (plain
// stores so L2 merges into the zeroed lines). Zeros already written by k_partzero.
__global__ __launch_bounds__(512) void k_scatter(const float4* __restrict__ info,
                                                 const float* __restrict__ lossp,
                                                 float* __restrict__ out) {
  const int tok = blockIdx.x * 512 + threadIdx.x;
  if (tok == 0) {
    float sv = 0.f;
    for (int b = 0; b < BB; ++b) sv += lossp[b];
    out[2 * SZ] = 0.5f * sv;   // * E^2 / (B*E) = *0.5
  }
  const float4 inf = info[tok];
  const int   pos0 = __float_as_int(inf.x);
  const int   pos1 = __float_as_int(inf.z);

  float* disp = out + (size_t)tok * ROW;
  float* comb = out + SZ + (size_t)tok * ROW;
  if (pos0 >= 0) { disp[pos0] = 1.f; comb[pos0] = inf.y; }
  if (pos1 >= 0) { disp[pos1] = 1.f; comb[pos1] = inf.w; }
}

extern "C" void kernel_launch(void* const* d_in, const int* in_sizes, int n_in,
                              void* d_out, int out_size, void* d_ws, size_t ws_size,
                              hipStream_t stream) {
  const float* x = (const float*)d_in[0];
  const float* w = (const float*)d_in[1];
  float* out = (float*)d_out;

  // ws layout: part (2,359,296 f = 9,437,184 B) | info (18432 float4 = 294,912 B) | lossp (32 f)
  float*  part  = (float*)d_ws;
  float4* info  = (float4*)((char*)d_ws + 9437184);
  float*  lossp = (float*)((char*)d_ws + 9437184 + 294912);

  hipLaunchKernelGGL(k_partzero, dim3(512), dim3(576), 0, stream, x, w, part, out);
  hipLaunchKernelGGL(k_gate,     dim3(BB),  dim3(576), 0, stream, part, info, lossp);
  hipLaunchKernelGGL(k_scatter,  dim3(36),  dim3(512), 0, stream, info, lossp, out);
}

// Round 14
// 110.035 us; speedup vs baseline: 1.2478x; 1.2478x over previous
//
#include <hip/hip_runtime.h>

#define TT 4
#define BB 32
#define DD 512
#define NN 576
#define EE 16
#define DC 8
#define DCH 64              // D-values per chunk
#define CC 144
#define ROW (EE*CC)         // 2304
#define SZ 42467328UL       // B*N*E*C

typedef float f4 __attribute__((ext_vector_type(4)));

// ---------------- Kernel 1: partial logits (t-inner pooling, 16-deep batches) ----------------
// grid (32, 8), block 576. R10 body with unroll 4: 16 loads in flight per wave.
__global__ __launch_bounds__(576) void k_part(const float* __restrict__ x,
                                              const float* __restrict__ w,
                                              float* __restrict__ part) {
  const int b  = blockIdx.x;
  const int dc = blockIdx.y;
  const int n  = threadIdx.x;
  const int d0 = dc * DCH;

  const float* xp = x + ((size_t)b * DD + d0) * NN + n;
  const size_t TS = (size_t)BB * DD * NN;   // t-plane stride in floats

  float acc[EE];
#pragma unroll
  for (int e = 0; e < EE; ++e) acc[e] = 0.f;

#pragma unroll 4
  for (int dd = 0; dd < DCH; ++dd) {
    const size_t o = (size_t)dd * NN;
    const float x0 = xp[o];
    const float x1 = xp[o + TS];
    const float x2 = xp[o + 2 * TS];
    const float x3 = xp[o + 3 * TS];
    const float xs = (x0 + x1) + (x2 + x3);
    const float* wd = w + (size_t)(d0 + dd) * EE;   // wave-uniform -> s_load
#pragma unroll
    for (int e = 0; e < EE; ++e) acc[e] = fmaf(xs, wd[e], acc[e]);
  }

  float4* dst4 = (float4*)(part + (((size_t)b * NN + n) * DC + dc) * EE);
#pragma unroll
  for (int q = 0; q < 4; ++q)
    dst4[q] = make_float4(acc[4*q], acc[4*q+1], acc[4*q+2], acc[4*q+3]);
}

// ---------------- Kernel 2: softmax, top-2, capacity scan (ballot-based) ----------------
// grid 32 (one per b), block 576 (one per token).
__global__ __launch_bounds__(576) void k_gate(const float* __restrict__ part,
                                              float4* __restrict__ info,
                                              float* __restrict__ lossp) {
  const int b = blockIdx.x;
  const int n = threadIdx.x;
  const int wave = n >> 6, lane = n & 63;

  __shared__ float sprox[9][EE];
  __shared__ int   swc1[9][EE];
  __shared__ int   swc2[9][EE];
  __shared__ int   woff1[9][EE];
  __shared__ int   woff2[9][EE];
  __shared__ float sproxTot[EE];
  __shared__ int   scnt0[EE];
  __shared__ int   sbase2[EE];

  // reduce partials -> logits (mean over T folded as *0.25)
  float l[EE];
#pragma unroll
  for (int e = 0; e < EE; ++e) l[e] = 0.f;
  {
    const float4* p4 = (const float4*)(part + (size_t)(b * NN + n) * (DC * EE));
#pragma unroll
    for (int dc = 0; dc < DC; ++dc) {
#pragma unroll
      for (int q = 0; q < 4; ++q) {
        float4 v = p4[dc * 4 + q];
        l[4*q+0] += v.x; l[4*q+1] += v.y; l[4*q+2] += v.z; l[4*q+3] += v.w;
      }
    }
#pragma unroll
    for (int e = 0; e < EE; ++e) l[e] *= 0.25f;
  }

  // softmax
  float m = l[0];
#pragma unroll
  for (int e = 1; e < EE; ++e) m = fmaxf(m, l[e]);
  float raw[EE]; float s = 0.f;
#pragma unroll
  for (int e = 0; e < EE; ++e) { raw[e] = expf(l[e] - m); s += raw[e]; }
  float inv = 1.f / s;
#pragma unroll
  for (int e = 0; e < EE; ++e) raw[e] *= inv;

  // top-1 / top-2 (first-index tie-break, matching jnp.argmax)
  int e1 = 0; float g1 = raw[0];
#pragma unroll
  for (int e = 1; e < EE; ++e) if (raw[e] > g1) { g1 = raw[e]; e1 = e; }
  int e2 = (e1 == 0) ? 1 : 0; float g2 = raw[e2];
#pragma unroll
  for (int e = 0; e < EE; ++e) if (e != e1 && raw[e] > g2) { g2 = raw[e]; e2 = e; }
  const float denom = g1 + g2 + 1e-9f;
  const float w0 = g1 / denom, w1 = g2 / denom;

  // ballot-based per-expert ranks: for each expert, 64-bit membership mask
  const unsigned long long ltm = (1ull << lane) - 1ull;
  int pre1 = 0, pre2 = 0;
#pragma unroll
  for (int e = 0; e < EE; ++e) {
    unsigned long long m1 = __ballot(e1 == e);
    unsigned long long m2 = __ballot(e2 == e);
    if (lane == 0) { swc1[wave][e] = __popcll(m1); swc2[wave][e] = __popcll(m2); }
    if (e == e1) pre1 = __popcll(m1 & ltm);
    if (e == e2) pre2 = __popcll(m2 & ltm);
  }

  // per-wave proxy (softmax sums) reduce
#pragma unroll
  for (int e = 0; e < EE; ++e) {
    float v = raw[e];
#pragma unroll
    for (int off = 32; off; off >>= 1) v += __shfl_xor(v, off);
    if (lane == 0) sprox[wave][e] = v;
  }
  __syncthreads();

  // cross-wave exclusive scan per expert (16 threads, 9 iters each)
  if (n < EE) {
    int r1 = 0, r2 = 0; float pv = 0.f;
#pragma unroll
    for (int wv = 0; wv < 9; ++wv) {
      woff1[wv][n] = r1; r1 += swc1[wv][n];
      woff2[wv][n] = r2; r2 += swc2[wv][n];
      pv += sprox[wv][n];
    }
    scnt0[n]    = r1;                     // pre-capacity top-1 count (for loss)
    sbase2[n]   = r1 < CC ? r1 : CC;      // post-truncation kept count (k=1 base)
    sproxTot[n] = pv;
  }
  __syncthreads();

  if (n == 0) {
    float S = 0.f;
    for (int e = 0; e < EE; ++e) S += sproxTot[e] * (float)scnt0[e];
    lossp[b] = S / ((float)NN * (float)NN);
  }

  const int p0 = woff1[wave][e1] + pre1;
  const int p1 = sbase2[e2] + woff2[wave][e2] + pre2;

  const int  pos0 = (p0 < CC) ? (e1 * CC + p0) : -1;
  const int  pos1 = (p1 < CC) ? (e2 * CC + p1) : -1;
  const float w0k = (p0 < CC) ? w0 : 0.f;
  const float w1k = (p1 < CC) ? w1 : 0.f;

  float4 o;
  o.x = __int_as_float(pos0);
  o.y = w0k;
  o.z = __int_as_float(pos1);
  o.w = w1k;
  info[b * NN + n] = o;
}

// ---------------- Kernel 3: write dispatch + combine + loss (NT, phase-split) ----------------
// grid 2304 (8 tokens per block), block 576. Phase 1: the block's 8 dispatch
// rows (one contiguous 73.7 KB region); phase 2: the 8 combine rows. NT stores
// kept (R5's win); stream separation avoids NT write-combine thrash between
// the two regions 170 MB apart.
__global__ __launch_bounds__(576) void k_write(const float4* __restrict__ info,
                                               const float* __restrict__ lossp,
                                               float* __restrict__ out) {
  const int blk  = blockIdx.x;
  const int tid  = threadIdx.x;
  const int tok0 = blk * 8;

  if (blk == 0 && tid == 0) {
    float sv = 0.f;
    for (int b = 0; b < BB; ++b) sv += lossp[b];
    out[2 * SZ] = 0.5f * sv;   // * E^2 / (B*E) = *0.5
  }

  __shared__ float4 sinfo[8];
  if (tid < 8) sinfo[tid] = info[tok0 + tid];
  __syncthreads();

  const int f0 = tid * 4;

  // phase 1: dispatch rows
#pragma unroll
  for (int it = 0; it < 8; ++it) {
    const float4 inf = sinfo[it];
    const int pos0 = __float_as_int(inf.x);
    const int pos1 = __float_as_int(inf.z);
    f4* disp = (f4*)(out + (size_t)(tok0 + it) * ROW);
    f4 dv = { (f0+0 == pos0 || f0+0 == pos1) ? 1.f : 0.f,
              (f0+1 == pos0 || f0+1 == pos1) ? 1.f : 0.f,
              (f0+2 == pos0 || f0+2 == pos1) ? 1.f : 0.f,
              (f0+3 == pos0 || f0+3 == pos1) ? 1.f : 0.f };
    __builtin_nontemporal_store(dv, &disp[tid]);
  }

  // phase 2: combine rows
#pragma unroll
  for (int it = 0; it < 8; ++it) {
    const float4 inf = sinfo[it];
    const int   pos0 = __float_as_int(inf.x);
    const float w0   = inf.y;
    const int   pos1 = __float_as_int(inf.z);
    const float w1   = inf.w;
    f4* comb = (f4*)(out + SZ + (size_t)(tok0 + it) * ROW);
    f4 cv = { (f0+0 == pos0) ? w0 : ((f0+0 == pos1) ? w1 : 0.f),
              (f0+1 == pos0) ? w0 : ((f0+1 == pos1) ? w1 : 0.f),
              (f0+2 == pos0) ? w0 : ((f0+2 == pos1) ? w1 : 0.f),
              (f0+3 == pos0) ? w0 : ((f0+3 == pos1) ? w1 : 0.f) };
    __builtin_nontemporal_store(cv, &comb[tid]);
  }
}

extern "C" void kernel_launch(void* const* d_in, const int* in_sizes, int n_in,
                              void* d_out, int out_size, void* d_ws, size_t ws_size,
                              hipStream_t stream) {
  const float* x = (const float*)d_in[0];
  const float* w = (const float*)d_in[1];
  float* out = (float*)d_out;

  // ws layout: part (2,359,296 f = 9,437,184 B) | info (18432 float4 = 294,912 B) | lossp (32 f)
  float*  part  = (float*)d_ws;
  float4* info  = (float4*)((char*)d_ws + 9437184);
  float*  lossp = (float*)((char*)d_ws + 9437184 + 294912);

  hipLaunchKernelGGL(k_part,  dim3(BB, DC), dim3(576), 0, stream, x, w, part);
  hipLaunchKernelGGL(k_gate,  dim3(BB),     dim3(576), 0, stream, part, info, lossp);
  hipLaunchKernelGGL(k_write, dim3(BB*NN/8), dim3(576), 0, stream, info, lossp, out);
}